// Round 5
// baseline (4196.223 us; speedup 1.0000x reference)
//
#include <hip/hip_runtime.h>

#define NEGV -1e30f
#define STR 36   // LDS row stride (floats): 16B-aligned + bank-uniform

__device__ __forceinline__ float4 ld4(const float* p) {
  return *reinterpret_cast<const float4*>(p);
}

__device__ __forceinline__ void fma8(float (&acc)[8], float4 w0, float4 w1, float a) {
  acc[0] = fmaf(a, w0.x, acc[0]);
  acc[1] = fmaf(a, w0.y, acc[1]);
  acc[2] = fmaf(a, w0.z, acc[2]);
  acc[3] = fmaf(a, w0.w, acc[3]);
  acc[4] = fmaf(a, w1.x, acc[4]);
  acc[5] = fmaf(a, w1.y, acc[5]);
  acc[6] = fmaf(a, w1.z, acc[6]);
  acc[7] = fmaf(a, w1.w, acc[7]);
}

// 2 samples per block (weight loads amortized 2x), 4 waves of 256 threads.
// Wave w owns rows 8w..8w+7 of BOTH samples (h0[8], h1[8]; lane = channel).
// qkv k/v + wo + MLP run in column-GEMM mode: per d, ONE coalesced weight
// load feeds 16 fma (8 rows x 2 samples); activation LDS reads are
// wave-uniform b128 broadcasts (conflict-free). q stays row-mode with
// half-wave-broadcast weight loads shared across both samples.
// LDS per sample: SA (aT -> kT -> oT), SB (vT -> m1T). 4 tiles = 38 KB ->
// 4 blocks/CU. 4 barriers/layer serve 2 samples.
//
// NOTE: the attention score/PV phase must NOT select register arrays via
// runtime pointers (`t ? qa1 : qa0`) -- that address-exposes them and LLVM
// allocates them in scratch (measured: +100 MB WRITE_SIZE, VGPR_Count
// dropped to 64 with hidden spills). Compile-time-bound array references
// (lambda parameters) keep them in VGPRs.
__launch_bounds__(256, 4)
__global__ void dwf_kernel(
    const float* __restrict__ x,
    const float* __restrict__ tok_emb,
    const float* __restrict__ pos_emb,
    const float* __restrict__ ln1_g, const float* __restrict__ ln1_b,
    const float* __restrict__ wqkv,  const float* __restrict__ bqkv,
    const float* __restrict__ wo,    const float* __restrict__ bo,
    const float* __restrict__ ln2_g, const float* __restrict__ ln2_b,
    const float* __restrict__ w1,    const float* __restrict__ b1,
    const float* __restrict__ w2,    const float* __restrict__ b2,
    const float* __restrict__ lnf_g, const float* __restrict__ lnf_b,
    const float* __restrict__ w_out, const float* __restrict__ b_out,
    const float* __restrict__ wp1,   const float* __restrict__ bp1,
    const float* __restrict__ wp2,   const float* __restrict__ bp2,
    const float* __restrict__ wp3,   const float* __restrict__ bp3,
    float* __restrict__ out, int out_pairs, int nB)
{
  const int s2   = blockIdx.x;      // sample pair index
  const int tid  = threadIdx.x;
  const int w    = tid >> 6;        // wave 0..3 (owns rows 8w..8w+7)
  const int lane = tid & 63;        // channel
  const int i32  = tid & 31;        // row (attention q-assignment)
  const int hh   = tid >> 5;        // head 0..7 (half-wave slot)
  const int g    = (tid >> 5) & 1;  // logit-column selector (per-wave)
  const bool valid1 = (2 * s2 + 1) < nB;

  __shared__ float SA0[64 * STR], SA1[64 * STR];
  __shared__ float SB0[64 * STR], SB1[64 * STR];
  __shared__ float xs[128], phb[128];
  __shared__ int   pis[64], toks[64];

  const float* xbase = x + s2 * 128;
  if (tid < 128) xs[tid] = (tid < 64 || valid1) ? xbase[tid] : 0.f;

  unsigned long long um = 0ull, dm = 0ull;
  if (w < 2) {
    int ub = 0, db = 0;
    if (lane < 32 && (w == 0 || valid1)) {
      const float* xr = xbase + 64 * w;
      ub = xr[2 * i32]     > 0.f;
      db = xr[2 * i32 + 1] > 0.f;
    }
    um = __ballot(ub);   // lanes>=32 contribute 0
    dm = __ballot(db);
    int pi   = ub + 2 * db;
    int prev = __shfl_up(pi, 1);
    if (lane < 32) {
      pis[32 * w + i32]  = pi;
      toks[32 * w + i32] = (i32 == 0) ? 4 : prev;
    }
  }
  __syncthreads();

  float h0[8], h1[8];
  #pragma unroll
  for (int q = 0; q < 8; ++q) {
    int r = 8 * w + q;
    float pe = pos_emb[r * 64 + lane];
    h0[q] = tok_emb[toks[r] * 64 + lane]      + pe;
    h1[q] = tok_emb[toks[32 + r] * 64 + lane] + pe;
  }

  // LN both samples with one weight load; interleaved shuffles for ILP.
  auto layernorm2 = [&](const float* gp, const float* bp) {
    float gv = gp[lane], bv = bp[lane];
    float va[8], vb[8];
    #pragma unroll
    for (int q = 0; q < 8; ++q) {
      float sa = h0[q], qa_ = h0[q] * h0[q];
      float sb = h1[q], qb_ = h1[q] * h1[q];
      #pragma unroll
      for (int off = 32; off; off >>= 1) {
        sa  += __shfl_xor(sa, off);
        qa_ += __shfl_xor(qa_, off);
        sb  += __shfl_xor(sb, off);
        qb_ += __shfl_xor(qb_, off);
      }
      float ma = sa * 0.015625f, mb = sb * 0.015625f;
      float ra = rsqrtf(fmaf(-ma, ma, qa_ * 0.015625f) + 1e-5f);
      float rb = rsqrtf(fmaf(-mb, mb, qb_ * 0.015625f) + 1e-5f);
      va[q] = fmaf((h0[q] - ma) * ra, gv, bv);
      vb[q] = fmaf((h1[q] - mb) * rb, gv, bv);
    }
    *reinterpret_cast<float4*>(&SA0[lane * STR + 8 * w])     = make_float4(va[0], va[1], va[2], va[3]);
    *reinterpret_cast<float4*>(&SA0[lane * STR + 8 * w + 4]) = make_float4(va[4], va[5], va[6], va[7]);
    *reinterpret_cast<float4*>(&SA1[lane * STR + 8 * w])     = make_float4(vb[0], vb[1], vb[2], vb[3]);
    *reinterpret_cast<float4*>(&SA1[lane * STR + 8 * w + 4]) = make_float4(vb[4], vb[5], vb[6], vb[7]);
  };

  // Score/softmax/PV for one sample. KT/VT are LDS pointers (fine); qa/oa are
  // compile-time-bound register-array references (must stay in VGPRs).
  auto attend = [&](const float* KT, const float* VT,
                    const float (&qa)[8], float (&oa)[8]) {
    float p[32];
    #pragma unroll
    for (int j4 = 0; j4 < 8; ++j4) {
      float a0 = 0.f, a1 = 0.f, a2 = 0.f, a3 = 0.f;
      #pragma unroll
      for (int c = 0; c < 8; ++c) {
        float4 kv = ld4(&KT[(8 * hh + c) * STR + 4 * j4]);
        a0 = fmaf(qa[c], kv.x, a0);
        a1 = fmaf(qa[c], kv.y, a1);
        a2 = fmaf(qa[c], kv.z, a2);
        a3 = fmaf(qa[c], kv.w, a3);
      }
      p[4 * j4]     = a0;
      p[4 * j4 + 1] = a1;
      p[4 * j4 + 2] = a2;
      p[4 * j4 + 3] = a3;
    }
    float mx = NEGV;
    #pragma unroll
    for (int j = 0; j < 32; ++j) {
      p[j] = (j <= i32) ? p[j] : NEGV;
      mx = fmaxf(mx, p[j]);
    }
    float sum = 0.f;
    #pragma unroll
    for (int j = 0; j < 32; ++j) {
      p[j] = __expf(p[j] - mx);
      sum += p[j];
    }
    float inv = 1.0f / sum;
    #pragma unroll
    for (int j = 0; j < 32; ++j) p[j] *= inv;

    #pragma unroll
    for (int e = 0; e < 8; ++e) {
      float acc = 0.f;
      #pragma unroll
      for (int j4 = 0; j4 < 8; ++j4) {
        float4 vv = ld4(&VT[(8 * hh + e) * STR + 4 * j4]);
        acc = fmaf(p[4 * j4],     vv.x, acc);
        acc = fmaf(p[4 * j4 + 1], vv.y, acc);
        acc = fmaf(p[4 * j4 + 2], vv.z, acc);
        acc = fmaf(p[4 * j4 + 3], vv.w, acc);
      }
      oa[e] = acc;
    }
  };

  for (int l = 0; l < 6; ++l) {
    // ---------------- attention ----------------
    layernorm2(ln1_g + l * 64, ln1_b + l * 64);
    __syncthreads();   // (A) aT read cross-wave next

    const float* wl = wqkv + l * 64 * 192;
    const float* bq = bqkv + l * 192;
    float qa0[8], qa1[8];
    #pragma unroll
    for (int e = 0; e < 8; ++e) { qa0[e] = bq[8 * hh + e]; qa1[e] = qa0[e]; }
    float kb = bq[64 + lane], vbb = bq[128 + lane];
    float k0a[8], k1a[8], v0a[8], v1a[8];
    #pragma unroll
    for (int q = 0; q < 8; ++q) { k0a[q] = kb; k1a[q] = kb; v0a[q] = vbb; v1a[q] = vbb; }

    // q: row-mode (broadcast weights, shared across samples).
    // k,v: column-mode (coalesced dword weights; wave-uniform LDS b128).
    #pragma unroll 2
    for (int d = 0; d < 64; ++d) {
      const float* wr = wl + d * 192;
      float4 wq0 = ld4(wr + 8 * hh);
      float4 wq1 = ld4(wr + 8 * hh + 4);
      float  wk  = wr[64 + lane];
      float  wv  = wr[128 + lane];
      float  av0 = SA0[d * STR + i32];
      float  av1 = SA1[d * STR + i32];
      float4 a0l = ld4(&SA0[d * STR + 8 * w]);
      float4 a0h = ld4(&SA0[d * STR + 8 * w + 4]);
      float4 a1l = ld4(&SA1[d * STR + 8 * w]);
      float4 a1h = ld4(&SA1[d * STR + 8 * w + 4]);
      fma8(qa0, wq0, wq1, av0);
      fma8(qa1, wq0, wq1, av1);
      fma8(k0a, a0l, a0h, wk);
      fma8(k1a, a1l, a1h, wk);
      fma8(v0a, a0l, a0h, wv);
      fma8(v1a, a1l, a1h, wv);
    }
    // fold softmax scale into q
    #pragma unroll
    for (int e = 0; e < 8; ++e) {
      qa0[e] *= 0.35355339059327373f;
      qa1[e] *= 0.35355339059327373f;
    }
    __syncthreads();   // (B) all aT reads done; SA may be overwritten

    // stage kT -> SA (over aT), vT -> SB; layout [channel][row]
    *reinterpret_cast<float4*>(&SA0[lane * STR + 8 * w])     = make_float4(k0a[0], k0a[1], k0a[2], k0a[3]);
    *reinterpret_cast<float4*>(&SA0[lane * STR + 8 * w + 4]) = make_float4(k0a[4], k0a[5], k0a[6], k0a[7]);
    *reinterpret_cast<float4*>(&SA1[lane * STR + 8 * w])     = make_float4(k1a[0], k1a[1], k1a[2], k1a[3]);
    *reinterpret_cast<float4*>(&SA1[lane * STR + 8 * w + 4]) = make_float4(k1a[4], k1a[5], k1a[6], k1a[7]);
    *reinterpret_cast<float4*>(&SB0[lane * STR + 8 * w])     = make_float4(v0a[0], v0a[1], v0a[2], v0a[3]);
    *reinterpret_cast<float4*>(&SB0[lane * STR + 8 * w + 4]) = make_float4(v0a[4], v0a[5], v0a[6], v0a[7]);
    *reinterpret_cast<float4*>(&SB1[lane * STR + 8 * w])     = make_float4(v1a[0], v1a[1], v1a[2], v1a[3]);
    *reinterpret_cast<float4*>(&SB1[lane * STR + 8 * w + 4]) = make_float4(v1a[4], v1a[5], v1a[6], v1a[7]);
    __syncthreads();   // (B2) kT/vT visible cross-wave

    // scores/softmax/o per sample; thread = (row i32, head hh)
    float oa0[8], oa1[8];
    attend(SA0, SB0, qa0, oa0);
    attend(SA1, SB1, qa1, oa1);

    // oT -> SA over own head's kT rows (same half-wave; in-order, no barrier)
    #pragma unroll
    for (int e = 0; e < 8; ++e) {
      SA0[(8 * hh + e) * STR + i32] = oa0[e];
      SA1[(8 * hh + e) * STR + i32] = oa1[e];
    }
    __syncthreads();   // (C) oT read cross-wave next

    // h += oT * wo  (own 8 rows, both samples; one weight load per d)
    const float* wop = wo + l * 4096 + lane;
    #pragma unroll 2
    for (int d = 0; d < 64; ++d) {
      float wv = wop[d * 64];
      float4 o0l = ld4(&SA0[d * STR + 8 * w]);
      float4 o0h = ld4(&SA0[d * STR + 8 * w + 4]);
      float4 o1l = ld4(&SA1[d * STR + 8 * w]);
      float4 o1h = ld4(&SA1[d * STR + 8 * w + 4]);
      fma8(h0, o0l, o0h, wv);
      fma8(h1, o1l, o1h, wv);
    }
    {
      float bov = bo[l * 64 + lane];
      #pragma unroll
      for (int q = 0; q < 8; ++q) { h0[q] += bov; h1[q] += bov; }
    }
    // no barrier: wo reads + LN2 writes touch the same own-wave region

    // ---------------- MLP (no internal barriers; own-wave traffic) ----------
    layernorm2(ln2_g + l * 64, ln2_b + l * 64);
    const float* w1base = w1 + l * 64 * 256;
    const float* w2base = w2 + l * 256 * 64;
    for (int cc = 0; cc < 4; ++cc) {
      float b1v = b1[l * 256 + cc * 64 + lane];
      float m0[8], m1v[8];
      #pragma unroll
      for (int q = 0; q < 8; ++q) { m0[q] = b1v; m1v[q] = b1v; }
      const float* w1p = w1base + cc * 64 + lane;
      #pragma unroll 2
      for (int d = 0; d < 64; ++d) {
        float wv = w1p[d * 256];
        float4 a0l = ld4(&SA0[d * STR + 8 * w]);
        float4 a0h = ld4(&SA0[d * STR + 8 * w + 4]);
        float4 a1l = ld4(&SA1[d * STR + 8 * w]);
        float4 a1h = ld4(&SA1[d * STR + 8 * w + 4]);
        fma8(m0,  a0l, a0h, wv);
        fma8(m1v, a1l, a1h, wv);
      }
      // m1T -> SB own cols (overwrites vT / prev m1T; vT last read pre-(C))
      *reinterpret_cast<float4*>(&SB0[lane * STR + 8 * w]) =
          make_float4(fmaxf(m0[0], 0.f), fmaxf(m0[1], 0.f),
                      fmaxf(m0[2], 0.f), fmaxf(m0[3], 0.f));
      *reinterpret_cast<float4*>(&SB0[lane * STR + 8 * w + 4]) =
          make_float4(fmaxf(m0[4], 0.f), fmaxf(m0[5], 0.f),
                      fmaxf(m0[6], 0.f), fmaxf(m0[7], 0.f));
      *reinterpret_cast<float4*>(&SB1[lane * STR + 8 * w]) =
          make_float4(fmaxf(m1v[0], 0.f), fmaxf(m1v[1], 0.f),
                      fmaxf(m1v[2], 0.f), fmaxf(m1v[3], 0.f));
      *reinterpret_cast<float4*>(&SB1[lane * STR + 8 * w + 4]) =
          make_float4(fmaxf(m1v[4], 0.f), fmaxf(m1v[5], 0.f),
                      fmaxf(m1v[6], 0.f), fmaxf(m1v[7], 0.f));
      const float* w2p = w2base + cc * 64 * 64 + lane;
      #pragma unroll 2
      for (int dc = 0; dc < 64; ++dc) {
        float wv = w2p[dc * 64];
        float4 q0l = ld4(&SB0[dc * STR + 8 * w]);
        float4 q0h = ld4(&SB0[dc * STR + 8 * w + 4]);
        float4 q1l = ld4(&SB1[dc * STR + 8 * w]);
        float4 q1h = ld4(&SB1[dc * STR + 8 * w + 4]);
        fma8(h0, q0l, q0h, wv);
        fma8(h1, q1l, q1h, wv);
      }
    }
    {
      float b2v = b2[l * 64 + lane];
      #pragma unroll
      for (int q = 0; q < 8; ++q) { h0[q] += b2v; h1[q] += b2v; }
    }
  }

  // ---------------- head: wave 0 -> sample 0, wave 1 -> sample 1 ------------
  layernorm2(lnf_g, lnf_b);
  __syncthreads();   // cross-wave logits reads

  if (w < 2) {
    const float* SAt = w ? SA1 : SA0;   // LDS pointer select: fine
    float la = b_out[2 * g], lb = b_out[2 * g + 1];
    #pragma unroll 4
    for (int d = 0; d < 64; ++d) {
      float av = SAt[d * STR + i32];
      la = fmaf(av, w_out[d * 4 + 2 * g],     la);
      lb = fmaf(av, w_out[d * 4 + 2 * g + 1], lb);
    }
    float lc  = __shfl_xor(la, 32);
    float ldt = __shfl_xor(lb, 32);

    int r   = i32;
    int nup = __popcll(um & ((1ull << r) - 1ull));
    int ndn = __popcll(dm & ((1ull << r) - 1ull));
    int rem = 31 - r;
    float lg[4] = {la, lb, lc, ldt};   // valid on lanes<32 (g=0)
    float ml[4];
    #pragma unroll
    for (int c = 0; c < 4; ++c) {
      int nu = nup + (c & 1);
      int nd = ndn + (c >> 1);
      bool ok = (nu <= 16) && (nd <= 16) && (16 - nu <= rem) && (16 - nd <= rem);
      ml[c] = ok ? lg[c] : NEGV;
    }
    float m4 = fmaxf(fmaxf(ml[0], ml[1]), fmaxf(ml[2], ml[3]));
    float se = __expf(ml[0] - m4) + __expf(ml[1] - m4) +
               __expf(ml[2] - m4) + __expf(ml[3] - m4);
    int c = pis[32 * w + r];
    float mls = (c == 0) ? ml[0] : (c == 1) ? ml[1] : (c == 2) ? ml[2] : ml[3];
    float amps = (lane < 32) ? (mls - m4 - __logf(se)) : 0.f;
    #pragma unroll
    for (int off = 32; off; off >>= 1) amps += __shfl_xor(amps, off);

    // phase MLP for own sample (in-wave LDS ordering; no barrier)
    const float* xst = xs + 64 * w;
    float p1 = bp1[lane];
    #pragma unroll 4
    for (int d = 0; d < 64; ++d)
      p1 = fmaf(xst[d], wp1[d * 64 + lane], p1);
    p1 = fmaxf(p1, 0.f);
    phb[64 * w + lane] = p1;
    float p2 = bp2[lane];
    #pragma unroll 4
    for (int d = 0; d < 64; ++d)
      p2 = fmaf(phb[64 * w + d], wp2[d * 64 + lane], p2);
    p2 = fmaxf(p2, 0.f);
    float p3 = p2 * wp3[lane];
    #pragma unroll
    for (int off = 32; off; off >>= 1) p3 += __shfl_xor(p3, off);
    float ph = p3 + bp3[0];

    if (lane == 0 && (w == 0 || valid1)) {
      int S = 2 * s2 + w;
      float amp = expf(0.5f * amps);
      if (out_pairs) {
        out[2 * S]     = amp * cosf(ph);
        out[2 * S + 1] = amp * sinf(ph);
      } else {
        // harness flattened complex64 via astype(float32): real part only
        out[S] = amp * cosf(ph);
      }
    }
  }
}

extern "C" void kernel_launch(void* const* d_in, const int* in_sizes, int n_in,
                              void* d_out, int out_size, void* d_ws, size_t ws_size,
                              hipStream_t stream) {
  (void)n_in; (void)d_ws; (void)ws_size;
  const int B = in_sizes[0] / 64;
  const int out_pairs = (out_size >= 2 * B) ? 1 : 0;
  const int grid = (B + 1) / 2;
  dwf_kernel<<<grid, 256, 0, stream>>>(
      (const float*)d_in[0],  (const float*)d_in[1],  (const float*)d_in[2],
      (const float*)d_in[3],  (const float*)d_in[4],  (const float*)d_in[5],
      (const float*)d_in[6],  (const float*)d_in[7],  (const float*)d_in[8],
      (const float*)d_in[9],  (const float*)d_in[10], (const float*)d_in[11],
      (const float*)d_in[12], (const float*)d_in[13], (const float*)d_in[14],
      (const float*)d_in[15], (const float*)d_in[16], (const float*)d_in[17],
      (const float*)d_in[18], (const float*)d_in[19], (const float*)d_in[20],
      (const float*)d_in[21], (const float*)d_in[22], (const float*)d_in[23],
      (const float*)d_in[24], (float*)d_out, out_pairs, B);
}

// Round 6
// 3437.015 us; speedup vs baseline: 1.2209x; 1.2209x over previous
//
#include <hip/hip_runtime.h>

#define NEGV -1e30f
#define STR 36   // LDS row stride (floats): 16B-aligned + bank-uniform

__device__ __forceinline__ float4 ld4(const float* p) {
  return *reinterpret_cast<const float4*>(p);
}

__device__ __forceinline__ void fma8(float (&acc)[8], float4 w0, float4 w1, float a) {
  acc[0] = fmaf(a, w0.x, acc[0]);
  acc[1] = fmaf(a, w0.y, acc[1]);
  acc[2] = fmaf(a, w0.z, acc[2]);
  acc[3] = fmaf(a, w0.w, acc[3]);
  acc[4] = fmaf(a, w1.x, acc[4]);
  acc[5] = fmaf(a, w1.y, acc[5]);
  acc[6] = fmaf(a, w1.z, acc[6]);
  acc[7] = fmaf(a, w1.w, acc[7]);
}

// 2 samples per block (weight loads amortized 2x), 4 waves of 256 threads.
// Wave w owns rows 8w..8w+7 of BOTH samples (h0[8], h1[8]; lane = channel).
// qkv k/v + wo + MLP run in column-GEMM mode: per d, ONE coalesced weight
// load feeds 16 fma (8 rows x 2 samples); activation LDS reads are
// wave-uniform b128 broadcasts (conflict-free). q stays row-mode with
// half-wave-broadcast weight loads shared across both samples.
// LDS per sample: SA (aT -> kT -> oT), SB (vT -> m1T). 4 tiles = 38 KB ->
// 4 blocks/CU. 4 barriers/layer serve 2 samples.
//
// SCRATCH RULE (measured rounds 4/5): the score/softmax/PV phase must be
// WRITTEN INLINE with direct array names. Selecting register arrays via
// runtime pointers (`t ? qa1 : qa0`) OR passing them by reference into a
// lambda address-exposes them -> SROA fails -> p[32]/qa/oa go to scratch
// (+0.1..0.8 GB of HBM traffic, VGPR_Count misleadingly drops to 64).
// fma8-style tiny leaf helpers are fine; big bodies are not.
__launch_bounds__(256, 4)
__global__ void dwf_kernel(
    const float* __restrict__ x,
    const float* __restrict__ tok_emb,
    const float* __restrict__ pos_emb,
    const float* __restrict__ ln1_g, const float* __restrict__ ln1_b,
    const float* __restrict__ wqkv,  const float* __restrict__ bqkv,
    const float* __restrict__ wo,    const float* __restrict__ bo,
    const float* __restrict__ ln2_g, const float* __restrict__ ln2_b,
    const float* __restrict__ w1,    const float* __restrict__ b1,
    const float* __restrict__ w2,    const float* __restrict__ b2,
    const float* __restrict__ lnf_g, const float* __restrict__ lnf_b,
    const float* __restrict__ w_out, const float* __restrict__ b_out,
    const float* __restrict__ wp1,   const float* __restrict__ bp1,
    const float* __restrict__ wp2,   const float* __restrict__ bp2,
    const float* __restrict__ wp3,   const float* __restrict__ bp3,
    float* __restrict__ out, int out_pairs, int nB)
{
  const int s2   = blockIdx.x;      // sample pair index
  const int tid  = threadIdx.x;
  const int w    = tid >> 6;        // wave 0..3 (owns rows 8w..8w+7)
  const int lane = tid & 63;        // channel
  const int i32  = tid & 31;        // row (attention q-assignment)
  const int hh   = tid >> 5;        // head 0..7 (half-wave slot)
  const int g    = (tid >> 5) & 1;  // logit-column selector (per-wave)
  const bool valid1 = (2 * s2 + 1) < nB;

  __shared__ float SA0[64 * STR], SA1[64 * STR];
  __shared__ float SB0[64 * STR], SB1[64 * STR];
  __shared__ float xs[128], phb[128];
  __shared__ int   pis[64], toks[64];

  const float* xbase = x + s2 * 128;
  if (tid < 128) xs[tid] = (tid < 64 || valid1) ? xbase[tid] : 0.f;

  unsigned long long um = 0ull, dm = 0ull;
  if (w < 2) {
    int ub = 0, db = 0;
    if (lane < 32 && (w == 0 || valid1)) {
      const float* xr = xbase + 64 * w;
      ub = xr[2 * i32]     > 0.f;
      db = xr[2 * i32 + 1] > 0.f;
    }
    um = __ballot(ub);   // lanes>=32 contribute 0
    dm = __ballot(db);
    int pi   = ub + 2 * db;
    int prev = __shfl_up(pi, 1);
    if (lane < 32) {
      pis[32 * w + i32]  = pi;
      toks[32 * w + i32] = (i32 == 0) ? 4 : prev;
    }
  }
  __syncthreads();

  float h0[8], h1[8];
  #pragma unroll
  for (int q = 0; q < 8; ++q) {
    int r = 8 * w + q;
    float pe = pos_emb[r * 64 + lane];
    h0[q] = tok_emb[toks[r] * 64 + lane]      + pe;
    h1[q] = tok_emb[toks[32 + r] * 64 + lane] + pe;
  }

  // LN both samples with one weight load; interleaved shuffles for ILP.
  auto layernorm2 = [&](const float* gp, const float* bp) {
    float gv = gp[lane], bv = bp[lane];
    float va[8], vb[8];
    #pragma unroll
    for (int q = 0; q < 8; ++q) {
      float sa = h0[q], qa_ = h0[q] * h0[q];
      float sb = h1[q], qb_ = h1[q] * h1[q];
      #pragma unroll
      for (int off = 32; off; off >>= 1) {
        sa  += __shfl_xor(sa, off);
        qa_ += __shfl_xor(qa_, off);
        sb  += __shfl_xor(sb, off);
        qb_ += __shfl_xor(qb_, off);
      }
      float ma = sa * 0.015625f, mb = sb * 0.015625f;
      float ra = rsqrtf(fmaf(-ma, ma, qa_ * 0.015625f) + 1e-5f);
      float rb = rsqrtf(fmaf(-mb, mb, qb_ * 0.015625f) + 1e-5f);
      va[q] = fmaf((h0[q] - ma) * ra, gv, bv);
      vb[q] = fmaf((h1[q] - mb) * rb, gv, bv);
    }
    *reinterpret_cast<float4*>(&SA0[lane * STR + 8 * w])     = make_float4(va[0], va[1], va[2], va[3]);
    *reinterpret_cast<float4*>(&SA0[lane * STR + 8 * w + 4]) = make_float4(va[4], va[5], va[6], va[7]);
    *reinterpret_cast<float4*>(&SA1[lane * STR + 8 * w])     = make_float4(vb[0], vb[1], vb[2], vb[3]);
    *reinterpret_cast<float4*>(&SA1[lane * STR + 8 * w + 4]) = make_float4(vb[4], vb[5], vb[6], vb[7]);
  };

  for (int l = 0; l < 6; ++l) {
    // ---------------- attention ----------------
    layernorm2(ln1_g + l * 64, ln1_b + l * 64);
    __syncthreads();   // (A) aT read cross-wave next

    const float* wl = wqkv + l * 64 * 192;
    const float* bq = bqkv + l * 192;
    float qa0[8], qa1[8];
    #pragma unroll
    for (int e = 0; e < 8; ++e) { qa0[e] = bq[8 * hh + e]; qa1[e] = qa0[e]; }
    float kb = bq[64 + lane], vbb = bq[128 + lane];
    float k0a[8], k1a[8], v0a[8], v1a[8];
    #pragma unroll
    for (int q = 0; q < 8; ++q) { k0a[q] = kb; k1a[q] = kb; v0a[q] = vbb; v1a[q] = vbb; }

    // q: row-mode (broadcast weights, shared across samples).
    // k,v: column-mode (coalesced dword weights; wave-uniform LDS b128).
    #pragma unroll 2
    for (int d = 0; d < 64; ++d) {
      const float* wr = wl + d * 192;
      float4 wq0 = ld4(wr + 8 * hh);
      float4 wq1 = ld4(wr + 8 * hh + 4);
      float  wk  = wr[64 + lane];
      float  wv  = wr[128 + lane];
      float  av0 = SA0[d * STR + i32];
      float  av1 = SA1[d * STR + i32];
      float4 a0l = ld4(&SA0[d * STR + 8 * w]);
      float4 a0h = ld4(&SA0[d * STR + 8 * w + 4]);
      float4 a1l = ld4(&SA1[d * STR + 8 * w]);
      float4 a1h = ld4(&SA1[d * STR + 8 * w + 4]);
      fma8(qa0, wq0, wq1, av0);
      fma8(qa1, wq0, wq1, av1);
      fma8(k0a, a0l, a0h, wk);
      fma8(k1a, a1l, a1h, wk);
      fma8(v0a, a0l, a0h, wv);
      fma8(v1a, a1l, a1h, wv);
    }
    // fold softmax scale into q
    #pragma unroll
    for (int e = 0; e < 8; ++e) {
      qa0[e] *= 0.35355339059327373f;
      qa1[e] *= 0.35355339059327373f;
    }
    __syncthreads();   // (B) all aT reads done; SA may be overwritten

    // stage kT -> SA (over aT), vT -> SB; layout [channel][row]
    *reinterpret_cast<float4*>(&SA0[lane * STR + 8 * w])     = make_float4(k0a[0], k0a[1], k0a[2], k0a[3]);
    *reinterpret_cast<float4*>(&SA0[lane * STR + 8 * w + 4]) = make_float4(k0a[4], k0a[5], k0a[6], k0a[7]);
    *reinterpret_cast<float4*>(&SA1[lane * STR + 8 * w])     = make_float4(k1a[0], k1a[1], k1a[2], k1a[3]);
    *reinterpret_cast<float4*>(&SA1[lane * STR + 8 * w + 4]) = make_float4(k1a[4], k1a[5], k1a[6], k1a[7]);
    *reinterpret_cast<float4*>(&SB0[lane * STR + 8 * w])     = make_float4(v0a[0], v0a[1], v0a[2], v0a[3]);
    *reinterpret_cast<float4*>(&SB0[lane * STR + 8 * w + 4]) = make_float4(v0a[4], v0a[5], v0a[6], v0a[7]);
    *reinterpret_cast<float4*>(&SB1[lane * STR + 8 * w])     = make_float4(v1a[0], v1a[1], v1a[2], v1a[3]);
    *reinterpret_cast<float4*>(&SB1[lane * STR + 8 * w + 4]) = make_float4(v1a[4], v1a[5], v1a[6], v1a[7]);
    __syncthreads();   // (B2) kT/vT visible cross-wave

    // ---- sample 0: scores/softmax/PV, oT stored directly (inline, no refs)
    {
      float p[32];
      #pragma unroll
      for (int j4 = 0; j4 < 8; ++j4) {
        float a0 = 0.f, a1 = 0.f, a2 = 0.f, a3 = 0.f;
        #pragma unroll
        for (int c = 0; c < 8; ++c) {
          float4 kv = ld4(&SA0[(8 * hh + c) * STR + 4 * j4]);
          a0 = fmaf(qa0[c], kv.x, a0);
          a1 = fmaf(qa0[c], kv.y, a1);
          a2 = fmaf(qa0[c], kv.z, a2);
          a3 = fmaf(qa0[c], kv.w, a3);
        }
        p[4 * j4]     = a0;
        p[4 * j4 + 1] = a1;
        p[4 * j4 + 2] = a2;
        p[4 * j4 + 3] = a3;
      }
      float mx = NEGV;
      #pragma unroll
      for (int j = 0; j < 32; ++j) {
        p[j] = (j <= i32) ? p[j] : NEGV;
        mx = fmaxf(mx, p[j]);
      }
      float sum = 0.f;
      #pragma unroll
      for (int j = 0; j < 32; ++j) {
        p[j] = __expf(p[j] - mx);
        sum += p[j];
      }
      float inv = 1.0f / sum;   // folded into PV epilogue
      #pragma unroll
      for (int e = 0; e < 8; ++e) {
        float acc = 0.f;
        #pragma unroll
        for (int j4 = 0; j4 < 8; ++j4) {
          float4 vv = ld4(&SB0[(8 * hh + e) * STR + 4 * j4]);
          acc = fmaf(p[4 * j4],     vv.x, acc);
          acc = fmaf(p[4 * j4 + 1], vv.y, acc);
          acc = fmaf(p[4 * j4 + 2], vv.z, acc);
          acc = fmaf(p[4 * j4 + 3], vv.w, acc);
        }
        SA0[(8 * hh + e) * STR + i32] = acc * inv;  // oT over own kT rows
      }
    }
    // ---- sample 1: identical, SA1/SB1/qa1
    {
      float p[32];
      #pragma unroll
      for (int j4 = 0; j4 < 8; ++j4) {
        float a0 = 0.f, a1 = 0.f, a2 = 0.f, a3 = 0.f;
        #pragma unroll
        for (int c = 0; c < 8; ++c) {
          float4 kv = ld4(&SA1[(8 * hh + c) * STR + 4 * j4]);
          a0 = fmaf(qa1[c], kv.x, a0);
          a1 = fmaf(qa1[c], kv.y, a1);
          a2 = fmaf(qa1[c], kv.z, a2);
          a3 = fmaf(qa1[c], kv.w, a3);
        }
        p[4 * j4]     = a0;
        p[4 * j4 + 1] = a1;
        p[4 * j4 + 2] = a2;
        p[4 * j4 + 3] = a3;
      }
      float mx = NEGV;
      #pragma unroll
      for (int j = 0; j < 32; ++j) {
        p[j] = (j <= i32) ? p[j] : NEGV;
        mx = fmaxf(mx, p[j]);
      }
      float sum = 0.f;
      #pragma unroll
      for (int j = 0; j < 32; ++j) {
        p[j] = __expf(p[j] - mx);
        sum += p[j];
      }
      float inv = 1.0f / sum;
      #pragma unroll
      for (int e = 0; e < 8; ++e) {
        float acc = 0.f;
        #pragma unroll
        for (int j4 = 0; j4 < 8; ++j4) {
          float4 vv = ld4(&SB1[(8 * hh + e) * STR + 4 * j4]);
          acc = fmaf(p[4 * j4],     vv.x, acc);
          acc = fmaf(p[4 * j4 + 1], vv.y, acc);
          acc = fmaf(p[4 * j4 + 2], vv.z, acc);
          acc = fmaf(p[4 * j4 + 3], vv.w, acc);
        }
        SA1[(8 * hh + e) * STR + i32] = acc * inv;
      }
    }
    __syncthreads();   // (C) oT read cross-wave next

    // h += oT * wo  (own 8 rows, both samples; one weight load per d)
    const float* wop = wo + l * 4096 + lane;
    #pragma unroll 2
    for (int d = 0; d < 64; ++d) {
      float wv = wop[d * 64];
      float4 o0l = ld4(&SA0[d * STR + 8 * w]);
      float4 o0h = ld4(&SA0[d * STR + 8 * w + 4]);
      float4 o1l = ld4(&SA1[d * STR + 8 * w]);
      float4 o1h = ld4(&SA1[d * STR + 8 * w + 4]);
      fma8(h0, o0l, o0h, wv);
      fma8(h1, o1l, o1h, wv);
    }
    {
      float bov = bo[l * 64 + lane];
      #pragma unroll
      for (int q = 0; q < 8; ++q) { h0[q] += bov; h1[q] += bov; }
    }
    // no barrier: wo reads + LN2 writes touch the same own-wave region

    // ---------------- MLP (no internal barriers; own-wave traffic) ----------
    layernorm2(ln2_g + l * 64, ln2_b + l * 64);
    const float* w1base = w1 + l * 64 * 256;
    const float* w2base = w2 + l * 256 * 64;
    for (int cc = 0; cc < 4; ++cc) {
      float b1v = b1[l * 256 + cc * 64 + lane];
      float m0[8], m1v[8];
      #pragma unroll
      for (int q = 0; q < 8; ++q) { m0[q] = b1v; m1v[q] = b1v; }
      const float* w1p = w1base + cc * 64 + lane;
      #pragma unroll 2
      for (int d = 0; d < 64; ++d) {
        float wv = w1p[d * 256];
        float4 a0l = ld4(&SA0[d * STR + 8 * w]);
        float4 a0h = ld4(&SA0[d * STR + 8 * w + 4]);
        float4 a1l = ld4(&SA1[d * STR + 8 * w]);
        float4 a1h = ld4(&SA1[d * STR + 8 * w + 4]);
        fma8(m0,  a0l, a0h, wv);
        fma8(m1v, a1l, a1h, wv);
      }
      // m1T -> SB own cols (overwrites vT / prev m1T; vT last read pre-(C))
      *reinterpret_cast<float4*>(&SB0[lane * STR + 8 * w]) =
          make_float4(fmaxf(m0[0], 0.f), fmaxf(m0[1], 0.f),
                      fmaxf(m0[2], 0.f), fmaxf(m0[3], 0.f));
      *reinterpret_cast<float4*>(&SB0[lane * STR + 8 * w + 4]) =
          make_float4(fmaxf(m0[4], 0.f), fmaxf(m0[5], 0.f),
                      fmaxf(m0[6], 0.f), fmaxf(m0[7], 0.f));
      *reinterpret_cast<float4*>(&SB1[lane * STR + 8 * w]) =
          make_float4(fmaxf(m1v[0], 0.f), fmaxf(m1v[1], 0.f),
                      fmaxf(m1v[2], 0.f), fmaxf(m1v[3], 0.f));
      *reinterpret_cast<float4*>(&SB1[lane * STR + 8 * w + 4]) =
          make_float4(fmaxf(m1v[4], 0.f), fmaxf(m1v[5], 0.f),
                      fmaxf(m1v[6], 0.f), fmaxf(m1v[7], 0.f));
      const float* w2p = w2base + cc * 64 * 64 + lane;
      #pragma unroll 2
      for (int dc = 0; dc < 64; ++dc) {
        float wv = w2p[dc * 64];
        float4 q0l = ld4(&SB0[dc * STR + 8 * w]);
        float4 q0h = ld4(&SB0[dc * STR + 8 * w + 4]);
        float4 q1l = ld4(&SB1[dc * STR + 8 * w]);
        float4 q1h = ld4(&SB1[dc * STR + 8 * w + 4]);
        fma8(h0, q0l, q0h, wv);
        fma8(h1, q1l, q1h, wv);
      }
    }
    {
      float b2v = b2[l * 64 + lane];
      #pragma unroll
      for (int q = 0; q < 8; ++q) { h0[q] += b2v; h1[q] += b2v; }
    }
  }

  // ---------------- head: wave 0 -> sample 0, wave 1 -> sample 1 ------------
  layernorm2(lnf_g, lnf_b);
  __syncthreads();   // cross-wave logits reads

  if (w < 2) {
    const float* SAt = w ? SA1 : SA0;   // LDS pointer select: fine
    float la = b_out[2 * g], lb = b_out[2 * g + 1];
    #pragma unroll 4
    for (int d = 0; d < 64; ++d) {
      float av = SAt[d * STR + i32];
      la = fmaf(av, w_out[d * 4 + 2 * g],     la);
      lb = fmaf(av, w_out[d * 4 + 2 * g + 1], lb);
    }
    float lc  = __shfl_xor(la, 32);
    float ldt = __shfl_xor(lb, 32);

    int r   = i32;
    int nup = __popcll(um & ((1ull << r) - 1ull));
    int ndn = __popcll(dm & ((1ull << r) - 1ull));
    int rem = 31 - r;
    float lg[4] = {la, lb, lc, ldt};   // valid on lanes<32 (g=0)
    float ml[4];
    #pragma unroll
    for (int c = 0; c < 4; ++c) {
      int nu = nup + (c & 1);
      int nd = ndn + (c >> 1);
      bool ok = (nu <= 16) && (nd <= 16) && (16 - nu <= rem) && (16 - nd <= rem);
      ml[c] = ok ? lg[c] : NEGV;
    }
    float m4 = fmaxf(fmaxf(ml[0], ml[1]), fmaxf(ml[2], ml[3]));
    float se = __expf(ml[0] - m4) + __expf(ml[1] - m4) +
               __expf(ml[2] - m4) + __expf(ml[3] - m4);
    int c = pis[32 * w + r];
    float mls = (c == 0) ? ml[0] : (c == 1) ? ml[1] : (c == 2) ? ml[2] : ml[3];
    float amps = (lane < 32) ? (mls - m4 - __logf(se)) : 0.f;
    #pragma unroll
    for (int off = 32; off; off >>= 1) amps += __shfl_xor(amps, off);

    // phase MLP for own sample (in-wave LDS ordering; no barrier)
    const float* xst = xs + 64 * w;
    float p1 = bp1[lane];
    #pragma unroll 4
    for (int d = 0; d < 64; ++d)
      p1 = fmaf(xst[d], wp1[d * 64 + lane], p1);
    p1 = fmaxf(p1, 0.f);
    phb[64 * w + lane] = p1;
    float p2 = bp2[lane];
    #pragma unroll 4
    for (int d = 0; d < 64; ++d)
      p2 = fmaf(phb[64 * w + d], wp2[d * 64 + lane], p2);
    p2 = fmaxf(p2, 0.f);
    float p3 = p2 * wp3[lane];
    #pragma unroll
    for (int off = 32; off; off >>= 1) p3 += __shfl_xor(p3, off);
    float ph = p3 + bp3[0];

    if (lane == 0 && (w == 0 || valid1)) {
      int S = 2 * s2 + w;
      float amp = expf(0.5f * amps);
      if (out_pairs) {
        out[2 * S]     = amp * cosf(ph);
        out[2 * S + 1] = amp * sinf(ph);
      } else {
        // harness flattened complex64 via astype(float32): real part only
        out[S] = amp * cosf(ph);
      }
    }
  }
}

extern "C" void kernel_launch(void* const* d_in, const int* in_sizes, int n_in,
                              void* d_out, int out_size, void* d_ws, size_t ws_size,
                              hipStream_t stream) {
  (void)n_in; (void)d_ws; (void)ws_size;
  const int B = in_sizes[0] / 64;
  const int out_pairs = (out_size >= 2 * B) ? 1 : 0;
  const int grid = (B + 1) / 2;
  dwf_kernel<<<grid, 256, 0, stream>>>(
      (const float*)d_in[0],  (const float*)d_in[1],  (const float*)d_in[2],
      (const float*)d_in[3],  (const float*)d_in[4],  (const float*)d_in[5],
      (const float*)d_in[6],  (const float*)d_in[7],  (const float*)d_in[8],
      (const float*)d_in[9],  (const float*)d_in[10], (const float*)d_in[11],
      (const float*)d_in[12], (const float*)d_in[13], (const float*)d_in[14],
      (const float*)d_in[15], (const float*)d_in[16], (const float*)d_in[17],
      (const float*)d_in[18], (const float*)d_in[19], (const float*)d_in[20],
      (const float*)d_in[21], (const float*)d_in[22], (const float*)d_in[23],
      (const float*)d_in[24], (float*)d_out, out_pairs, B);
}

// Round 7
// 2951.414 us; speedup vs baseline: 1.4218x; 1.1645x over previous
//
#include <hip/hip_runtime.h>

#define NEGV -1e30f
#define STR 36   // LDS row stride (floats): 16B-aligned + bank-uniform

__device__ __forceinline__ float4 ld4(const float* p) {
  return *reinterpret_cast<const float4*>(p);
}

__device__ __forceinline__ void fma8(float (&acc)[8], float4 w0, float4 w1, float a) {
  acc[0] = fmaf(a, w0.x, acc[0]);
  acc[1] = fmaf(a, w0.y, acc[1]);
  acc[2] = fmaf(a, w0.z, acc[2]);
  acc[3] = fmaf(a, w0.w, acc[3]);
  acc[4] = fmaf(a, w1.x, acc[4]);
  acc[5] = fmaf(a, w1.y, acc[5]);
  acc[6] = fmaf(a, w1.z, acc[6]);
  acc[7] = fmaf(a, w1.w, acc[7]);
}

// 2 samples per block (weight loads amortized 2x), 4 waves of 256 threads.
// Wave w owns rows 8w..8w+7 of BOTH samples (h0[8], h1[8]; lane = channel).
// qkv k/v + wo + MLP run in column-GEMM mode: per d, ONE coalesced weight
// load feeds 16 fma (8 rows x 2 samples); activation LDS reads are
// wave-uniform b128 broadcasts (conflict-free). q stays row-mode with
// half-wave-broadcast weight loads shared across both samples.
// LDS per sample: SA (aT -> kT -> oT), SB (vT -> m1T). 4 tiles = 38 KB ->
// 4 blocks/CU (LDS-bound). 4 barriers/layer serve 2 samples.
//
// SCRATCH RULE (measured rounds 4/5): the score/softmax/PV phase must be
// WRITTEN INLINE with direct array names. Selecting register arrays via
// runtime pointers (`t ? qa1 : qa0`) OR passing them by reference into a
// lambda address-exposes them -> SROA fails -> p[32]/qa/oa go to scratch
// (+0.1..0.8 GB of HBM traffic, VGPR_Count misleadingly drops to 64).
// fma8-style tiny leaf helpers are fine; big bodies are not.
//
// LAUNCH_BOUNDS RULE (measured rounds 1/2/6): the allocator targets ~2x the
// declared min-waves occupancy and SPILLS to reach it (min=6 -> 40 VGPR,
// min=4 -> 64 VGPR, both with scratch traffic). LDS caps occupancy at
// 4 waves/EU, so declare min=2: allocator targets 4 waves/EU and can use
// the ~100-128 VGPRs the live set (p[32]+h0/h1+qa0/qa1) actually needs.
__launch_bounds__(256, 2)
__global__ void dwf_kernel(
    const float* __restrict__ x,
    const float* __restrict__ tok_emb,
    const float* __restrict__ pos_emb,
    const float* __restrict__ ln1_g, const float* __restrict__ ln1_b,
    const float* __restrict__ wqkv,  const float* __restrict__ bqkv,
    const float* __restrict__ wo,    const float* __restrict__ bo,
    const float* __restrict__ ln2_g, const float* __restrict__ ln2_b,
    const float* __restrict__ w1,    const float* __restrict__ b1,
    const float* __restrict__ w2,    const float* __restrict__ b2,
    const float* __restrict__ lnf_g, const float* __restrict__ lnf_b,
    const float* __restrict__ w_out, const float* __restrict__ b_out,
    const float* __restrict__ wp1,   const float* __restrict__ bp1,
    const float* __restrict__ wp2,   const float* __restrict__ bp2,
    const float* __restrict__ wp3,   const float* __restrict__ bp3,
    float* __restrict__ out, int out_pairs, int nB)
{
  const int s2   = blockIdx.x;      // sample pair index
  const int tid  = threadIdx.x;
  const int w    = tid >> 6;        // wave 0..3 (owns rows 8w..8w+7)
  const int lane = tid & 63;        // channel
  const int i32  = tid & 31;        // row (attention q-assignment)
  const int hh   = tid >> 5;        // head 0..7 (half-wave slot)
  const int g    = (tid >> 5) & 1;  // logit-column selector (per-wave)
  const bool valid1 = (2 * s2 + 1) < nB;

  __shared__ float SA0[64 * STR], SA1[64 * STR];
  __shared__ float SB0[64 * STR], SB1[64 * STR];
  __shared__ float xs[128], phb[128];
  __shared__ int   pis[64], toks[64];

  const float* xbase = x + s2 * 128;
  if (tid < 128) xs[tid] = (tid < 64 || valid1) ? xbase[tid] : 0.f;

  unsigned long long um = 0ull, dm = 0ull;
  if (w < 2) {
    int ub = 0, db = 0;
    if (lane < 32 && (w == 0 || valid1)) {
      const float* xr = xbase + 64 * w;
      ub = xr[2 * i32]     > 0.f;
      db = xr[2 * i32 + 1] > 0.f;
    }
    um = __ballot(ub);   // lanes>=32 contribute 0
    dm = __ballot(db);
    int pi   = ub + 2 * db;
    int prev = __shfl_up(pi, 1);
    if (lane < 32) {
      pis[32 * w + i32]  = pi;
      toks[32 * w + i32] = (i32 == 0) ? 4 : prev;
    }
  }
  __syncthreads();

  float h0[8], h1[8];
  #pragma unroll
  for (int q = 0; q < 8; ++q) {
    int r = 8 * w + q;
    float pe = pos_emb[r * 64 + lane];
    h0[q] = tok_emb[toks[r] * 64 + lane]      + pe;
    h1[q] = tok_emb[toks[32 + r] * 64 + lane] + pe;
  }

  // LN both samples with one weight load; interleaved shuffles for ILP.
  auto layernorm2 = [&](const float* gp, const float* bp) {
    float gv = gp[lane], bv = bp[lane];
    float va[8], vb[8];
    #pragma unroll
    for (int q = 0; q < 8; ++q) {
      float sa = h0[q], qa_ = h0[q] * h0[q];
      float sb = h1[q], qb_ = h1[q] * h1[q];
      #pragma unroll
      for (int off = 32; off; off >>= 1) {
        sa  += __shfl_xor(sa, off);
        qa_ += __shfl_xor(qa_, off);
        sb  += __shfl_xor(sb, off);
        qb_ += __shfl_xor(qb_, off);
      }
      float ma = sa * 0.015625f, mb = sb * 0.015625f;
      float ra = rsqrtf(fmaf(-ma, ma, qa_ * 0.015625f) + 1e-5f);
      float rb = rsqrtf(fmaf(-mb, mb, qb_ * 0.015625f) + 1e-5f);
      va[q] = fmaf((h0[q] - ma) * ra, gv, bv);
      vb[q] = fmaf((h1[q] - mb) * rb, gv, bv);
    }
    *reinterpret_cast<float4*>(&SA0[lane * STR + 8 * w])     = make_float4(va[0], va[1], va[2], va[3]);
    *reinterpret_cast<float4*>(&SA0[lane * STR + 8 * w + 4]) = make_float4(va[4], va[5], va[6], va[7]);
    *reinterpret_cast<float4*>(&SA1[lane * STR + 8 * w])     = make_float4(vb[0], vb[1], vb[2], vb[3]);
    *reinterpret_cast<float4*>(&SA1[lane * STR + 8 * w + 4]) = make_float4(vb[4], vb[5], vb[6], vb[7]);
  };

  for (int l = 0; l < 6; ++l) {
    // ---------------- attention ----------------
    layernorm2(ln1_g + l * 64, ln1_b + l * 64);
    __syncthreads();   // (A) aT read cross-wave next

    const float* wl = wqkv + l * 64 * 192;
    const float* bq = bqkv + l * 192;
    float qa0[8], qa1[8];
    #pragma unroll
    for (int e = 0; e < 8; ++e) { qa0[e] = bq[8 * hh + e]; qa1[e] = qa0[e]; }
    float kb = bq[64 + lane], vbb = bq[128 + lane];
    float k0a[8], k1a[8], v0a[8], v1a[8];
    #pragma unroll
    for (int q = 0; q < 8; ++q) { k0a[q] = kb; k1a[q] = kb; v0a[q] = vbb; v1a[q] = vbb; }

    // q: row-mode (broadcast weights, shared across samples).
    // k,v: column-mode (coalesced dword weights; wave-uniform LDS b128).
    #pragma unroll 2
    for (int d = 0; d < 64; ++d) {
      const float* wr = wl + d * 192;
      float4 wq0 = ld4(wr + 8 * hh);
      float4 wq1 = ld4(wr + 8 * hh + 4);
      float  wk  = wr[64 + lane];
      float  wv  = wr[128 + lane];
      float  av0 = SA0[d * STR + i32];
      float  av1 = SA1[d * STR + i32];
      float4 a0l = ld4(&SA0[d * STR + 8 * w]);
      float4 a0h = ld4(&SA0[d * STR + 8 * w + 4]);
      float4 a1l = ld4(&SA1[d * STR + 8 * w]);
      float4 a1h = ld4(&SA1[d * STR + 8 * w + 4]);
      fma8(qa0, wq0, wq1, av0);
      fma8(qa1, wq0, wq1, av1);
      fma8(k0a, a0l, a0h, wk);
      fma8(k1a, a1l, a1h, wk);
      fma8(v0a, a0l, a0h, wv);
      fma8(v1a, a1l, a1h, wv);
    }
    // fold softmax scale into q
    #pragma unroll
    for (int e = 0; e < 8; ++e) {
      qa0[e] *= 0.35355339059327373f;
      qa1[e] *= 0.35355339059327373f;
    }
    __syncthreads();   // (B) all aT reads done; SA may be overwritten

    // stage kT -> SA (over aT), vT -> SB; layout [channel][row]
    *reinterpret_cast<float4*>(&SA0[lane * STR + 8 * w])     = make_float4(k0a[0], k0a[1], k0a[2], k0a[3]);
    *reinterpret_cast<float4*>(&SA0[lane * STR + 8 * w + 4]) = make_float4(k0a[4], k0a[5], k0a[6], k0a[7]);
    *reinterpret_cast<float4*>(&SA1[lane * STR + 8 * w])     = make_float4(k1a[0], k1a[1], k1a[2], k1a[3]);
    *reinterpret_cast<float4*>(&SA1[lane * STR + 8 * w + 4]) = make_float4(k1a[4], k1a[5], k1a[6], k1a[7]);
    *reinterpret_cast<float4*>(&SB0[lane * STR + 8 * w])     = make_float4(v0a[0], v0a[1], v0a[2], v0a[3]);
    *reinterpret_cast<float4*>(&SB0[lane * STR + 8 * w + 4]) = make_float4(v0a[4], v0a[5], v0a[6], v0a[7]);
    *reinterpret_cast<float4*>(&SB1[lane * STR + 8 * w])     = make_float4(v1a[0], v1a[1], v1a[2], v1a[3]);
    *reinterpret_cast<float4*>(&SB1[lane * STR + 8 * w + 4]) = make_float4(v1a[4], v1a[5], v1a[6], v1a[7]);
    __syncthreads();   // (B2) kT/vT visible cross-wave

    // ---- sample 0: scores/softmax/PV, oT stored directly (inline, no refs)
    {
      float p[32];
      #pragma unroll
      for (int j4 = 0; j4 < 8; ++j4) {
        float a0 = 0.f, a1 = 0.f, a2 = 0.f, a3 = 0.f;
        #pragma unroll
        for (int c = 0; c < 8; ++c) {
          float4 kv = ld4(&SA0[(8 * hh + c) * STR + 4 * j4]);
          a0 = fmaf(qa0[c], kv.x, a0);
          a1 = fmaf(qa0[c], kv.y, a1);
          a2 = fmaf(qa0[c], kv.z, a2);
          a3 = fmaf(qa0[c], kv.w, a3);
        }
        p[4 * j4]     = a0;
        p[4 * j4 + 1] = a1;
        p[4 * j4 + 2] = a2;
        p[4 * j4 + 3] = a3;
      }
      float mx = NEGV;
      #pragma unroll
      for (int j = 0; j < 32; ++j) {
        p[j] = (j <= i32) ? p[j] : NEGV;
        mx = fmaxf(mx, p[j]);
      }
      float sum = 0.f;
      #pragma unroll
      for (int j = 0; j < 32; ++j) {
        p[j] = __expf(p[j] - mx);
        sum += p[j];
      }
      float inv = 1.0f / sum;   // folded into PV epilogue
      #pragma unroll
      for (int e = 0; e < 8; ++e) {
        float acc = 0.f;
        #pragma unroll
        for (int j4 = 0; j4 < 8; ++j4) {
          float4 vv = ld4(&SB0[(8 * hh + e) * STR + 4 * j4]);
          acc = fmaf(p[4 * j4],     vv.x, acc);
          acc = fmaf(p[4 * j4 + 1], vv.y, acc);
          acc = fmaf(p[4 * j4 + 2], vv.z, acc);
          acc = fmaf(p[4 * j4 + 3], vv.w, acc);
        }
        SA0[(8 * hh + e) * STR + i32] = acc * inv;  // oT over own kT rows
      }
    }
    // ---- sample 1: identical, SA1/SB1/qa1
    {
      float p[32];
      #pragma unroll
      for (int j4 = 0; j4 < 8; ++j4) {
        float a0 = 0.f, a1 = 0.f, a2 = 0.f, a3 = 0.f;
        #pragma unroll
        for (int c = 0; c < 8; ++c) {
          float4 kv = ld4(&SA1[(8 * hh + c) * STR + 4 * j4]);
          a0 = fmaf(qa1[c], kv.x, a0);
          a1 = fmaf(qa1[c], kv.y, a1);
          a2 = fmaf(qa1[c], kv.z, a2);
          a3 = fmaf(qa1[c], kv.w, a3);
        }
        p[4 * j4]     = a0;
        p[4 * j4 + 1] = a1;
        p[4 * j4 + 2] = a2;
        p[4 * j4 + 3] = a3;
      }
      float mx = NEGV;
      #pragma unroll
      for (int j = 0; j < 32; ++j) {
        p[j] = (j <= i32) ? p[j] : NEGV;
        mx = fmaxf(mx, p[j]);
      }
      float sum = 0.f;
      #pragma unroll
      for (int j = 0; j < 32; ++j) {
        p[j] = __expf(p[j] - mx);
        sum += p[j];
      }
      float inv = 1.0f / sum;
      #pragma unroll
      for (int e = 0; e < 8; ++e) {
        float acc = 0.f;
        #pragma unroll
        for (int j4 = 0; j4 < 8; ++j4) {
          float4 vv = ld4(&SB1[(8 * hh + e) * STR + 4 * j4]);
          acc = fmaf(p[4 * j4],     vv.x, acc);
          acc = fmaf(p[4 * j4 + 1], vv.y, acc);
          acc = fmaf(p[4 * j4 + 2], vv.z, acc);
          acc = fmaf(p[4 * j4 + 3], vv.w, acc);
        }
        SA1[(8 * hh + e) * STR + i32] = acc * inv;
      }
    }
    __syncthreads();   // (C) oT read cross-wave next

    // h += oT * wo  (own 8 rows, both samples; one weight load per d)
    const float* wop = wo + l * 4096 + lane;
    #pragma unroll 2
    for (int d = 0; d < 64; ++d) {
      float wv = wop[d * 64];
      float4 o0l = ld4(&SA0[d * STR + 8 * w]);
      float4 o0h = ld4(&SA0[d * STR + 8 * w + 4]);
      float4 o1l = ld4(&SA1[d * STR + 8 * w]);
      float4 o1h = ld4(&SA1[d * STR + 8 * w + 4]);
      fma8(h0, o0l, o0h, wv);
      fma8(h1, o1l, o1h, wv);
    }
    {
      float bov = bo[l * 64 + lane];
      #pragma unroll
      for (int q = 0; q < 8; ++q) { h0[q] += bov; h1[q] += bov; }
    }
    // no barrier: wo reads + LN2 writes touch the same own-wave region

    // ---------------- MLP (no internal barriers; own-wave traffic) ----------
    layernorm2(ln2_g + l * 64, ln2_b + l * 64);
    const float* w1base = w1 + l * 64 * 256;
    const float* w2base = w2 + l * 256 * 64;
    for (int cc = 0; cc < 4; ++cc) {
      float b1v = b1[l * 256 + cc * 64 + lane];
      float m0[8], m1v[8];
      #pragma unroll
      for (int q = 0; q < 8; ++q) { m0[q] = b1v; m1v[q] = b1v; }
      const float* w1p = w1base + cc * 64 + lane;
      #pragma unroll 2
      for (int d = 0; d < 64; ++d) {
        float wv = w1p[d * 256];
        float4 a0l = ld4(&SA0[d * STR + 8 * w]);
        float4 a0h = ld4(&SA0[d * STR + 8 * w + 4]);
        float4 a1l = ld4(&SA1[d * STR + 8 * w]);
        float4 a1h = ld4(&SA1[d * STR + 8 * w + 4]);
        fma8(m0,  a0l, a0h, wv);
        fma8(m1v, a1l, a1h, wv);
      }
      // m1T -> SB own cols (overwrites vT / prev m1T; vT last read pre-(C))
      *reinterpret_cast<float4*>(&SB0[lane * STR + 8 * w]) =
          make_float4(fmaxf(m0[0], 0.f), fmaxf(m0[1], 0.f),
                      fmaxf(m0[2], 0.f), fmaxf(m0[3], 0.f));
      *reinterpret_cast<float4*>(&SB0[lane * STR + 8 * w + 4]) =
          make_float4(fmaxf(m0[4], 0.f), fmaxf(m0[5], 0.f),
                      fmaxf(m0[6], 0.f), fmaxf(m0[7], 0.f));
      *reinterpret_cast<float4*>(&SB1[lane * STR + 8 * w]) =
          make_float4(fmaxf(m1v[0], 0.f), fmaxf(m1v[1], 0.f),
                      fmaxf(m1v[2], 0.f), fmaxf(m1v[3], 0.f));
      *reinterpret_cast<float4*>(&SB1[lane * STR + 8 * w + 4]) =
          make_float4(fmaxf(m1v[4], 0.f), fmaxf(m1v[5], 0.f),
                      fmaxf(m1v[6], 0.f), fmaxf(m1v[7], 0.f));
      const float* w2p = w2base + cc * 64 * 64 + lane;
      #pragma unroll 2
      for (int dc = 0; dc < 64; ++dc) {
        float wv = w2p[dc * 64];
        float4 q0l = ld4(&SB0[dc * STR + 8 * w]);
        float4 q0h = ld4(&SB0[dc * STR + 8 * w + 4]);
        float4 q1l = ld4(&SB1[dc * STR + 8 * w]);
        float4 q1h = ld4(&SB1[dc * STR + 8 * w + 4]);
        fma8(h0, q0l, q0h, wv);
        fma8(h1, q1l, q1h, wv);
      }
    }
    {
      float b2v = b2[l * 64 + lane];
      #pragma unroll
      for (int q = 0; q < 8; ++q) { h0[q] += b2v; h1[q] += b2v; }
    }
  }

  // ---------------- head: wave 0 -> sample 0, wave 1 -> sample 1 ------------
  layernorm2(lnf_g, lnf_b);
  __syncthreads();   // cross-wave logits reads

  if (w < 2) {
    const float* SAt = w ? SA1 : SA0;   // LDS pointer select: fine
    float la = b_out[2 * g], lb = b_out[2 * g + 1];
    #pragma unroll 4
    for (int d = 0; d < 64; ++d) {
      float av = SAt[d * STR + i32];
      la = fmaf(av, w_out[d * 4 + 2 * g],     la);
      lb = fmaf(av, w_out[d * 4 + 2 * g + 1], lb);
    }
    float lc  = __shfl_xor(la, 32);
    float ldt = __shfl_xor(lb, 32);

    int r   = i32;
    int nup = __popcll(um & ((1ull << r) - 1ull));
    int ndn = __popcll(dm & ((1ull << r) - 1ull));
    int rem = 31 - r;
    float lg[4] = {la, lb, lc, ldt};   // valid on lanes<32 (g=0)
    float ml[4];
    #pragma unroll
    for (int c = 0; c < 4; ++c) {
      int nu = nup + (c & 1);
      int nd = ndn + (c >> 1);
      bool ok = (nu <= 16) && (nd <= 16) && (16 - nu <= rem) && (16 - nd <= rem);
      ml[c] = ok ? lg[c] : NEGV;
    }
    float m4 = fmaxf(fmaxf(ml[0], ml[1]), fmaxf(ml[2], ml[3]));
    float se = __expf(ml[0] - m4) + __expf(ml[1] - m4) +
               __expf(ml[2] - m4) + __expf(ml[3] - m4);
    int c = pis[32 * w + r];
    float mls = (c == 0) ? ml[0] : (c == 1) ? ml[1] : (c == 2) ? ml[2] : ml[3];
    float amps = (lane < 32) ? (mls - m4 - __logf(se)) : 0.f;
    #pragma unroll
    for (int off = 32; off; off >>= 1) amps += __shfl_xor(amps, off);

    // phase MLP for own sample (in-wave LDS ordering; no barrier)
    const float* xst = xs + 64 * w;
    float p1 = bp1[lane];
    #pragma unroll 4
    for (int d = 0; d < 64; ++d)
      p1 = fmaf(xst[d], wp1[d * 64 + lane], p1);
    p1 = fmaxf(p1, 0.f);
    phb[64 * w + lane] = p1;
    float p2 = bp2[lane];
    #pragma unroll 4
    for (int d = 0; d < 64; ++d)
      p2 = fmaf(phb[64 * w + d], wp2[d * 64 + lane], p2);
    p2 = fmaxf(p2, 0.f);
    float p3 = p2 * wp3[lane];
    #pragma unroll
    for (int off = 32; off; off >>= 1) p3 += __shfl_xor(p3, off);
    float ph = p3 + bp3[0];

    if (lane == 0 && (w == 0 || valid1)) {
      int S = 2 * s2 + w;
      float amp = expf(0.5f * amps);
      if (out_pairs) {
        out[2 * S]     = amp * cosf(ph);
        out[2 * S + 1] = amp * sinf(ph);
      } else {
        // harness flattened complex64 via astype(float32): real part only
        out[S] = amp * cosf(ph);
      }
    }
  }
}

extern "C" void kernel_launch(void* const* d_in, const int* in_sizes, int n_in,
                              void* d_out, int out_size, void* d_ws, size_t ws_size,
                              hipStream_t stream) {
  (void)n_in; (void)d_ws; (void)ws_size;
  const int B = in_sizes[0] / 64;
  const int out_pairs = (out_size >= 2 * B) ? 1 : 0;
  const int grid = (B + 1) / 2;
  dwf_kernel<<<grid, 256, 0, stream>>>(
      (const float*)d_in[0],  (const float*)d_in[1],  (const float*)d_in[2],
      (const float*)d_in[3],  (const float*)d_in[4],  (const float*)d_in[5],
      (const float*)d_in[6],  (const float*)d_in[7],  (const float*)d_in[8],
      (const float*)d_in[9],  (const float*)d_in[10], (const float*)d_in[11],
      (const float*)d_in[12], (const float*)d_in[13], (const float*)d_in[14],
      (const float*)d_in[15], (const float*)d_in[16], (const float*)d_in[17],
      (const float*)d_in[18], (const float*)d_in[19], (const float*)d_in[20],
      (const float*)d_in[21], (const float*)d_in[22], (const float*)d_in[23],
      (const float*)d_in[24], (float*)d_out, out_pairs, B);
}

// Round 8
// 2732.066 us; speedup vs baseline: 1.5359x; 1.0803x over previous
//
#include <hip/hip_runtime.h>

#define NEGV -1e30f
#define STR 36   // LDS row stride (floats): 16B-aligned + bank-uniform

__device__ __forceinline__ float4 ld4(const float* p) {
  return *reinterpret_cast<const float4*>(p);
}

__device__ __forceinline__ void fma8(float (&acc)[8], float4 w0, float4 w1, float a) {
  acc[0] = fmaf(a, w0.x, acc[0]);
  acc[1] = fmaf(a, w0.y, acc[1]);
  acc[2] = fmaf(a, w0.z, acc[2]);
  acc[3] = fmaf(a, w0.w, acc[3]);
  acc[4] = fmaf(a, w1.x, acc[4]);
  acc[5] = fmaf(a, w1.y, acc[5]);
  acc[6] = fmaf(a, w1.z, acc[6]);
  acc[7] = fmaf(a, w1.w, acc[7]);
}

// 2 samples per block, 4 waves of 256 threads. Wave w owns rows 8w..8w+7 of
// both samples (h0[8], h1[8]; lane = channel). Column-GEMM mode everywhere
// except attention q. LDS: SA0/1 (aT->kT->oT), SB0/1 (vT->m1T), 38.4 KB ->
// 4 blocks/CU (LDS-bound). 4 barriers/layer serve 2 samples.
//
// SCRATCH RULE (rounds 4/5): score/softmax/PV written inline with direct
// array names; never select register arrays via runtime pointers or pass
// them as (even reference) lambda/function ARRAY parameters. Lambdas that
// only CAPTURE arrays (layernorm2) are safe (round 7: no scratch).
// All prefetch buffers are indexed with compile-time constants only.
//
// LAUNCH_BOUNDS RULE (rounds 1/2/6): allocator targets ~2x declared
// min-waves and spills to get there; LDS caps us at 4 waves/EU, so declare
// min=2 (cap 256) and let it settle (round 7: 76 VGPR, zero scratch).
//
// PIPELINING (this round): weight streams are ping-pong strip-prefetched
// (depth ~4-8 iterations ~= 256-380 cy) to cover ~200 cy L2 latency that
// 4-wave TLP alone left exposed (VALUBusy 46%). MLP w1 is cc-blocked
// 2-wide: one aT b128 read feeds 32 fma instead of 16.
__launch_bounds__(256, 2)
__global__ void dwf_kernel(
    const float* __restrict__ x,
    const float* __restrict__ tok_emb,
    const float* __restrict__ pos_emb,
    const float* __restrict__ ln1_g, const float* __restrict__ ln1_b,
    const float* __restrict__ wqkv,  const float* __restrict__ bqkv,
    const float* __restrict__ wo,    const float* __restrict__ bo,
    const float* __restrict__ ln2_g, const float* __restrict__ ln2_b,
    const float* __restrict__ w1,    const float* __restrict__ b1,
    const float* __restrict__ w2,    const float* __restrict__ b2,
    const float* __restrict__ lnf_g, const float* __restrict__ lnf_b,
    const float* __restrict__ w_out, const float* __restrict__ b_out,
    const float* __restrict__ wp1,   const float* __restrict__ bp1,
    const float* __restrict__ wp2,   const float* __restrict__ bp2,
    const float* __restrict__ wp3,   const float* __restrict__ bp3,
    float* __restrict__ out, int out_pairs, int nB)
{
  const int s2   = blockIdx.x;      // sample pair index
  const int tid  = threadIdx.x;
  const int w    = tid >> 6;        // wave 0..3 (owns rows 8w..8w+7)
  const int lane = tid & 63;        // channel
  const int i32  = tid & 31;        // row (attention q-assignment)
  const int hh   = tid >> 5;        // head 0..7 (half-wave slot)
  const int g    = (tid >> 5) & 1;  // logit-column selector (per-wave)
  const bool valid1 = (2 * s2 + 1) < nB;

  __shared__ float SA0[64 * STR], SA1[64 * STR];
  __shared__ float SB0[64 * STR], SB1[64 * STR];
  __shared__ float xs[128], phb[128];
  __shared__ int   pis[64], toks[64];

  const float* xbase = x + s2 * 128;
  if (tid < 128) xs[tid] = (tid < 64 || valid1) ? xbase[tid] : 0.f;

  unsigned long long um = 0ull, dm = 0ull;
  if (w < 2) {
    int ub = 0, db = 0;
    if (lane < 32 && (w == 0 || valid1)) {
      const float* xr = xbase + 64 * w;
      ub = xr[2 * i32]     > 0.f;
      db = xr[2 * i32 + 1] > 0.f;
    }
    um = __ballot(ub);   // lanes>=32 contribute 0
    dm = __ballot(db);
    int pi   = ub + 2 * db;
    int prev = __shfl_up(pi, 1);
    if (lane < 32) {
      pis[32 * w + i32]  = pi;
      toks[32 * w + i32] = (i32 == 0) ? 4 : prev;
    }
  }
  __syncthreads();

  float h0[8], h1[8];
  #pragma unroll
  for (int q = 0; q < 8; ++q) {
    int r = 8 * w + q;
    float pe = pos_emb[r * 64 + lane];
    h0[q] = tok_emb[toks[r] * 64 + lane]      + pe;
    h1[q] = tok_emb[toks[32 + r] * 64 + lane] + pe;
  }

  // LN both samples with one weight load; interleaved shuffles for ILP.
  auto layernorm2 = [&](const float* gp, const float* bp) {
    float gv = gp[lane], bv = bp[lane];
    float va[8], vb[8];
    #pragma unroll
    for (int q = 0; q < 8; ++q) {
      float sa = h0[q], qa_ = h0[q] * h0[q];
      float sb = h1[q], qb_ = h1[q] * h1[q];
      #pragma unroll
      for (int off = 32; off; off >>= 1) {
        sa  += __shfl_xor(sa, off);
        qa_ += __shfl_xor(qa_, off);
        sb  += __shfl_xor(sb, off);
        qb_ += __shfl_xor(qb_, off);
      }
      float ma = sa * 0.015625f, mb = sb * 0.015625f;
      float ra = rsqrtf(fmaf(-ma, ma, qa_ * 0.015625f) + 1e-5f);
      float rb = rsqrtf(fmaf(-mb, mb, qb_ * 0.015625f) + 1e-5f);
      va[q] = fmaf((h0[q] - ma) * ra, gv, bv);
      vb[q] = fmaf((h1[q] - mb) * rb, gv, bv);
    }
    *reinterpret_cast<float4*>(&SA0[lane * STR + 8 * w])     = make_float4(va[0], va[1], va[2], va[3]);
    *reinterpret_cast<float4*>(&SA0[lane * STR + 8 * w + 4]) = make_float4(va[4], va[5], va[6], va[7]);
    *reinterpret_cast<float4*>(&SA1[lane * STR + 8 * w])     = make_float4(vb[0], vb[1], vb[2], vb[3]);
    *reinterpret_cast<float4*>(&SA1[lane * STR + 8 * w + 4]) = make_float4(vb[4], vb[5], vb[6], vb[7]);
  };

  // w2-style accumulation pass: reads SB (own cols), weight stream strip-8
  // ping-pong. Pointer-value param + array captures only (safe pattern).
  auto w2pass = [&](const float* w2p) {
    float gA[8], gB[8];
    #pragma unroll
    for (int u = 0; u < 8; ++u) gA[u] = w2p[u * 64];
    #pragma unroll 1
    for (int dp = 0; dp < 4; ++dp) {
      const int ds = dp * 16;
      #pragma unroll
      for (int u = 0; u < 8; ++u) gB[u] = w2p[((ds + 8 + u) & 63) * 64];
      #pragma unroll
      for (int u = 0; u < 8; ++u) {
        const int dc = ds + u;
        float4 q0l = ld4(&SB0[dc * STR + 8 * w]);
        float4 q0h = ld4(&SB0[dc * STR + 8 * w + 4]);
        float4 q1l = ld4(&SB1[dc * STR + 8 * w]);
        float4 q1h = ld4(&SB1[dc * STR + 8 * w + 4]);
        fma8(h0, q0l, q0h, gA[u]);
        fma8(h1, q1l, q1h, gA[u]);
      }
      #pragma unroll
      for (int u = 0; u < 8; ++u) gA[u] = w2p[((ds + 16 + u) & 63) * 64];
      #pragma unroll
      for (int u = 0; u < 8; ++u) {
        const int dc = ds + 8 + u;
        float4 q0l = ld4(&SB0[dc * STR + 8 * w]);
        float4 q0h = ld4(&SB0[dc * STR + 8 * w + 4]);
        float4 q1l = ld4(&SB1[dc * STR + 8 * w]);
        float4 q1h = ld4(&SB1[dc * STR + 8 * w + 4]);
        fma8(h0, q0l, q0h, gB[u]);
        fma8(h1, q1l, q1h, gB[u]);
      }
    }
  };

  for (int l = 0; l < 6; ++l) {
    // ---------------- attention ----------------
    layernorm2(ln1_g + l * 64, ln1_b + l * 64);
    __syncthreads();   // (A) aT read cross-wave next

    const float* wl = wqkv + l * 64 * 192;
    const float* bq = bqkv + l * 192;
    float qa0[8], qa1[8];
    #pragma unroll
    for (int e = 0; e < 8; ++e) { qa0[e] = bq[8 * hh + e]; qa1[e] = qa0[e]; }
    float kb = bq[64 + lane], vbb = bq[128 + lane];
    float k0a[8], k1a[8], v0a[8], v1a[8];
    #pragma unroll
    for (int q = 0; q < 8; ++q) { k0a[q] = kb; k1a[q] = kb; v0a[q] = vbb; v1a[q] = vbb; }

    // q row-mode; k,v column-mode with strip-4 ping-pong weight prefetch.
    const float* wkp = wl + 64 + lane;
    const float* wvp = wl + 128 + lane;
    float kwA[4], vwA[4], kwB[4], vwB[4];
    #pragma unroll
    for (int u = 0; u < 4; ++u) { kwA[u] = wkp[u * 192]; vwA[u] = wvp[u * 192]; }
    #pragma unroll 1
    for (int dp = 0; dp < 8; ++dp) {
      const int ds = dp * 8;
      #pragma unroll
      for (int u = 0; u < 4; ++u) {
        const int dn = (ds + 4 + u) & 63;
        kwB[u] = wkp[dn * 192]; vwB[u] = wvp[dn * 192];
      }
      #pragma unroll
      for (int u = 0; u < 4; ++u) {
        const int d = ds + u;
        const float* wr = wl + d * 192;
        float4 wq0 = ld4(wr + 8 * hh);
        float4 wq1 = ld4(wr + 8 * hh + 4);
        float  av0 = SA0[d * STR + i32];
        float  av1 = SA1[d * STR + i32];
        float4 a0l = ld4(&SA0[d * STR + 8 * w]);
        float4 a0h = ld4(&SA0[d * STR + 8 * w + 4]);
        float4 a1l = ld4(&SA1[d * STR + 8 * w]);
        float4 a1h = ld4(&SA1[d * STR + 8 * w + 4]);
        fma8(qa0, wq0, wq1, av0);
        fma8(qa1, wq0, wq1, av1);
        fma8(k0a, a0l, a0h, kwA[u]);
        fma8(k1a, a1l, a1h, kwA[u]);
        fma8(v0a, a0l, a0h, vwA[u]);
        fma8(v1a, a1l, a1h, vwA[u]);
      }
      #pragma unroll
      for (int u = 0; u < 4; ++u) {
        const int dn = (ds + 8 + u) & 63;
        kwA[u] = wkp[dn * 192]; vwA[u] = wvp[dn * 192];
      }
      #pragma unroll
      for (int u = 0; u < 4; ++u) {
        const int d = ds + 4 + u;
        const float* wr = wl + d * 192;
        float4 wq0 = ld4(wr + 8 * hh);
        float4 wq1 = ld4(wr + 8 * hh + 4);
        float  av0 = SA0[d * STR + i32];
        float  av1 = SA1[d * STR + i32];
        float4 a0l = ld4(&SA0[d * STR + 8 * w]);
        float4 a0h = ld4(&SA0[d * STR + 8 * w + 4]);
        float4 a1l = ld4(&SA1[d * STR + 8 * w]);
        float4 a1h = ld4(&SA1[d * STR + 8 * w + 4]);
        fma8(qa0, wq0, wq1, av0);
        fma8(qa1, wq0, wq1, av1);
        fma8(k0a, a0l, a0h, kwB[u]);
        fma8(k1a, a1l, a1h, kwB[u]);
        fma8(v0a, a0l, a0h, vwB[u]);
        fma8(v1a, a1l, a1h, vwB[u]);
      }
    }
    // fold softmax scale into q
    #pragma unroll
    for (int e = 0; e < 8; ++e) {
      qa0[e] *= 0.35355339059327373f;
      qa1[e] *= 0.35355339059327373f;
    }
    __syncthreads();   // (B) all aT reads done; SA may be overwritten

    // stage kT -> SA (over aT), vT -> SB; layout [channel][row]
    *reinterpret_cast<float4*>(&SA0[lane * STR + 8 * w])     = make_float4(k0a[0], k0a[1], k0a[2], k0a[3]);
    *reinterpret_cast<float4*>(&SA0[lane * STR + 8 * w + 4]) = make_float4(k0a[4], k0a[5], k0a[6], k0a[7]);
    *reinterpret_cast<float4*>(&SA1[lane * STR + 8 * w])     = make_float4(k1a[0], k1a[1], k1a[2], k1a[3]);
    *reinterpret_cast<float4*>(&SA1[lane * STR + 8 * w + 4]) = make_float4(k1a[4], k1a[5], k1a[6], k1a[7]);
    *reinterpret_cast<float4*>(&SB0[lane * STR + 8 * w])     = make_float4(v0a[0], v0a[1], v0a[2], v0a[3]);
    *reinterpret_cast<float4*>(&SB0[lane * STR + 8 * w + 4]) = make_float4(v0a[4], v0a[5], v0a[6], v0a[7]);
    *reinterpret_cast<float4*>(&SB1[lane * STR + 8 * w])     = make_float4(v1a[0], v1a[1], v1a[2], v1a[3]);
    *reinterpret_cast<float4*>(&SB1[lane * STR + 8 * w + 4]) = make_float4(v1a[4], v1a[5], v1a[6], v1a[7]);
    __syncthreads();   // (B2) kT/vT visible cross-wave

    // ---- sample 0: scores/softmax/PV, oT stored directly (inline, no refs)
    {
      float p[32];
      #pragma unroll
      for (int j4 = 0; j4 < 8; ++j4) {
        float a0 = 0.f, a1 = 0.f, a2 = 0.f, a3 = 0.f;
        #pragma unroll
        for (int c = 0; c < 8; ++c) {
          float4 kv = ld4(&SA0[(8 * hh + c) * STR + 4 * j4]);
          a0 = fmaf(qa0[c], kv.x, a0);
          a1 = fmaf(qa0[c], kv.y, a1);
          a2 = fmaf(qa0[c], kv.z, a2);
          a3 = fmaf(qa0[c], kv.w, a3);
        }
        p[4 * j4]     = a0;
        p[4 * j4 + 1] = a1;
        p[4 * j4 + 2] = a2;
        p[4 * j4 + 3] = a3;
      }
      float mx = NEGV;
      #pragma unroll
      for (int j = 0; j < 32; ++j) {
        p[j] = (j <= i32) ? p[j] : NEGV;
        mx = fmaxf(mx, p[j]);
      }
      float sum = 0.f;
      #pragma unroll
      for (int j = 0; j < 32; ++j) {
        p[j] = __expf(p[j] - mx);
        sum += p[j];
      }
      float inv = 1.0f / sum;   // folded into PV epilogue
      #pragma unroll
      for (int e = 0; e < 8; ++e) {
        float acc = 0.f;
        #pragma unroll
        for (int j4 = 0; j4 < 8; ++j4) {
          float4 vv = ld4(&SB0[(8 * hh + e) * STR + 4 * j4]);
          acc = fmaf(p[4 * j4],     vv.x, acc);
          acc = fmaf(p[4 * j4 + 1], vv.y, acc);
          acc = fmaf(p[4 * j4 + 2], vv.z, acc);
          acc = fmaf(p[4 * j4 + 3], vv.w, acc);
        }
        SA0[(8 * hh + e) * STR + i32] = acc * inv;  // oT over own kT rows
      }
    }
    // ---- sample 1: identical, SA1/SB1/qa1
    {
      float p[32];
      #pragma unroll
      for (int j4 = 0; j4 < 8; ++j4) {
        float a0 = 0.f, a1 = 0.f, a2 = 0.f, a3 = 0.f;
        #pragma unroll
        for (int c = 0; c < 8; ++c) {
          float4 kv = ld4(&SA1[(8 * hh + c) * STR + 4 * j4]);
          a0 = fmaf(qa1[c], kv.x, a0);
          a1 = fmaf(qa1[c], kv.y, a1);
          a2 = fmaf(qa1[c], kv.z, a2);
          a3 = fmaf(qa1[c], kv.w, a3);
        }
        p[4 * j4]     = a0;
        p[4 * j4 + 1] = a1;
        p[4 * j4 + 2] = a2;
        p[4 * j4 + 3] = a3;
      }
      float mx = NEGV;
      #pragma unroll
      for (int j = 0; j < 32; ++j) {
        p[j] = (j <= i32) ? p[j] : NEGV;
        mx = fmaxf(mx, p[j]);
      }
      float sum = 0.f;
      #pragma unroll
      for (int j = 0; j < 32; ++j) {
        p[j] = __expf(p[j] - mx);
        sum += p[j];
      }
      float inv = 1.0f / sum;
      #pragma unroll
      for (int e = 0; e < 8; ++e) {
        float acc = 0.f;
        #pragma unroll
        for (int j4 = 0; j4 < 8; ++j4) {
          float4 vv = ld4(&SB1[(8 * hh + e) * STR + 4 * j4]);
          acc = fmaf(p[4 * j4],     vv.x, acc);
          acc = fmaf(p[4 * j4 + 1], vv.y, acc);
          acc = fmaf(p[4 * j4 + 2], vv.z, acc);
          acc = fmaf(p[4 * j4 + 3], vv.w, acc);
        }
        SA1[(8 * hh + e) * STR + i32] = acc * inv;
      }
    }
    __syncthreads();   // (C) oT read cross-wave next

    // h += oT * wo  (own 8 rows, both samples; strip-8 ping-pong weights)
    {
      const float* wop = wo + l * 4096 + lane;
      float owA[8], owB[8];
      #pragma unroll
      for (int u = 0; u < 8; ++u) owA[u] = wop[u * 64];
      #pragma unroll 1
      for (int dp = 0; dp < 4; ++dp) {
        const int ds = dp * 16;
        #pragma unroll
        for (int u = 0; u < 8; ++u) owB[u] = wop[((ds + 8 + u) & 63) * 64];
        #pragma unroll
        for (int u = 0; u < 8; ++u) {
          const int d = ds + u;
          float4 o0l = ld4(&SA0[d * STR + 8 * w]);
          float4 o0h = ld4(&SA0[d * STR + 8 * w + 4]);
          float4 o1l = ld4(&SA1[d * STR + 8 * w]);
          float4 o1h = ld4(&SA1[d * STR + 8 * w + 4]);
          fma8(h0, o0l, o0h, owA[u]);
          fma8(h1, o1l, o1h, owA[u]);
        }
        #pragma unroll
        for (int u = 0; u < 8; ++u) owA[u] = wop[((ds + 16 + u) & 63) * 64];
        #pragma unroll
        for (int u = 0; u < 8; ++u) {
          const int d = ds + 8 + u;
          float4 o0l = ld4(&SA0[d * STR + 8 * w]);
          float4 o0h = ld4(&SA0[d * STR + 8 * w + 4]);
          float4 o1l = ld4(&SA1[d * STR + 8 * w]);
          float4 o1h = ld4(&SA1[d * STR + 8 * w + 4]);
          fma8(h0, o0l, o0h, owB[u]);
          fma8(h1, o1l, o1h, owB[u]);
        }
      }
      float bov = bo[l * 64 + lane];
      #pragma unroll
      for (int q = 0; q < 8; ++q) { h0[q] += bov; h1[q] += bov; }
    }
    // no barrier: wo reads + LN2 writes touch the same own-wave region

    // ---------------- MLP (no internal barriers; own-wave traffic) ----------
    layernorm2(ln2_g + l * 64, ln2_b + l * 64);
    const float* w1base = w1 + l * 64 * 256;
    const float* w2base = w2 + l * 256 * 64;
    #pragma unroll 1
    for (int ccp = 0; ccp < 2; ++ccp) {
      const int ccA = 2 * ccp, ccB = ccA + 1;
      float mA0[8], mA1[8], mB0[8], mB1[8];
      {
        float bA = b1[l * 256 + ccA * 64 + lane];
        float bB = b1[l * 256 + ccB * 64 + lane];
        #pragma unroll
        for (int q = 0; q < 8; ++q) { mA0[q] = bA; mA1[q] = bA; mB0[q] = bB; mB1[q] = bB; }
      }
      // w1: cc-blocked 2-wide, shared aT reads, dual strip-4 ping-pong streams
      const float* wpA = w1base + ccA * 64 + lane;  // stride 256
      const float* wpB = w1base + ccB * 64 + lane;
      float fA1[4], fB1[4], fA2[4], fB2[4];
      #pragma unroll
      for (int u = 0; u < 4; ++u) { fA1[u] = wpA[u * 256]; fB1[u] = wpB[u * 256]; }
      #pragma unroll 1
      for (int dp = 0; dp < 8; ++dp) {
        const int ds = dp * 8;
        #pragma unroll
        for (int u = 0; u < 4; ++u) {
          const int dn = (ds + 4 + u) & 63;
          fA2[u] = wpA[dn * 256]; fB2[u] = wpB[dn * 256];
        }
        #pragma unroll
        for (int u = 0; u < 4; ++u) {
          const int d = ds + u;
          float4 a0l = ld4(&SA0[d * STR + 8 * w]);
          float4 a0h = ld4(&SA0[d * STR + 8 * w + 4]);
          float4 a1l = ld4(&SA1[d * STR + 8 * w]);
          float4 a1h = ld4(&SA1[d * STR + 8 * w + 4]);
          fma8(mA0, a0l, a0h, fA1[u]);
          fma8(mA1, a1l, a1h, fA1[u]);
          fma8(mB0, a0l, a0h, fB1[u]);
          fma8(mB1, a1l, a1h, fB1[u]);
        }
        #pragma unroll
        for (int u = 0; u < 4; ++u) {
          const int dn = (ds + 8 + u) & 63;
          fA1[u] = wpA[dn * 256]; fB1[u] = wpB[dn * 256];
        }
        #pragma unroll
        for (int u = 0; u < 4; ++u) {
          const int d = ds + 4 + u;
          float4 a0l = ld4(&SA0[d * STR + 8 * w]);
          float4 a0h = ld4(&SA0[d * STR + 8 * w + 4]);
          float4 a1l = ld4(&SA1[d * STR + 8 * w]);
          float4 a1h = ld4(&SA1[d * STR + 8 * w + 4]);
          fma8(mA0, a0l, a0h, fA2[u]);
          fma8(mA1, a1l, a1h, fA2[u]);
          fma8(mB0, a0l, a0h, fB2[u]);
          fma8(mB1, a1l, a1h, fB2[u]);
        }
      }
      // chunk A: relu -> SB own cols, then w2 accumulate (same-wave, no barrier)
      *reinterpret_cast<float4*>(&SB0[lane * STR + 8 * w]) =
          make_float4(fmaxf(mA0[0], 0.f), fmaxf(mA0[1], 0.f),
                      fmaxf(mA0[2], 0.f), fmaxf(mA0[3], 0.f));
      *reinterpret_cast<float4*>(&SB0[lane * STR + 8 * w + 4]) =
          make_float4(fmaxf(mA0[4], 0.f), fmaxf(mA0[5], 0.f),
                      fmaxf(mA0[6], 0.f), fmaxf(mA0[7], 0.f));
      *reinterpret_cast<float4*>(&SB1[lane * STR + 8 * w]) =
          make_float4(fmaxf(mA1[0], 0.f), fmaxf(mA1[1], 0.f),
                      fmaxf(mA1[2], 0.f), fmaxf(mA1[3], 0.f));
      *reinterpret_cast<float4*>(&SB1[lane * STR + 8 * w + 4]) =
          make_float4(fmaxf(mA1[4], 0.f), fmaxf(mA1[5], 0.f),
                      fmaxf(mA1[6], 0.f), fmaxf(mA1[7], 0.f));
      w2pass(w2base + ccA * 64 * 64 + lane);
      // chunk B: overwrite SB (w2-A reads complete in-order, same wave)
      *reinterpret_cast<float4*>(&SB0[lane * STR + 8 * w]) =
          make_float4(fmaxf(mB0[0], 0.f), fmaxf(mB0[1], 0.f),
                      fmaxf(mB0[2], 0.f), fmaxf(mB0[3], 0.f));
      *reinterpret_cast<float4*>(&SB0[lane * STR + 8 * w + 4]) =
          make_float4(fmaxf(mB0[4], 0.f), fmaxf(mB0[5], 0.f),
                      fmaxf(mB0[6], 0.f), fmaxf(mB0[7], 0.f));
      *reinterpret_cast<float4*>(&SB1[lane * STR + 8 * w]) =
          make_float4(fmaxf(mB1[0], 0.f), fmaxf(mB1[1], 0.f),
                      fmaxf(mB1[2], 0.f), fmaxf(mB1[3], 0.f));
      *reinterpret_cast<float4*>(&SB1[lane * STR + 8 * w + 4]) =
          make_float4(fmaxf(mB1[4], 0.f), fmaxf(mB1[5], 0.f),
                      fmaxf(mB1[6], 0.f), fmaxf(mB1[7], 0.f));
      w2pass(w2base + ccB * 64 * 64 + lane);
    }
    {
      float b2v = b2[l * 64 + lane];
      #pragma unroll
      for (int q = 0; q < 8; ++q) { h0[q] += b2v; h1[q] += b2v; }
    }
  }

  // ---------------- head: wave 0 -> sample 0, wave 1 -> sample 1 ------------
  layernorm2(lnf_g, lnf_b);
  __syncthreads();   // cross-wave logits reads

  if (w < 2) {
    const float* SAt = w ? SA1 : SA0;   // LDS pointer select: fine
    float la = b_out[2 * g], lb = b_out[2 * g + 1];
    #pragma unroll 4
    for (int d = 0; d < 64; ++d) {
      float av = SAt[d * STR + i32];
      la = fmaf(av, w_out[d * 4 + 2 * g],     la);
      lb = fmaf(av, w_out[d * 4 + 2 * g + 1], lb);
    }
    float lc  = __shfl_xor(la, 32);
    float ldt = __shfl_xor(lb, 32);

    int r   = i32;
    int nup = __popcll(um & ((1ull << r) - 1ull));
    int ndn = __popcll(dm & ((1ull << r) - 1ull));
    int rem = 31 - r;
    float lg[4] = {la, lb, lc, ldt};   // valid on lanes<32 (g=0)
    float ml[4];
    #pragma unroll
    for (int c = 0; c < 4; ++c) {
      int nu = nup + (c & 1);
      int nd = ndn + (c >> 1);
      bool ok = (nu <= 16) && (nd <= 16) && (16 - nu <= rem) && (16 - nd <= rem);
      ml[c] = ok ? lg[c] : NEGV;
    }
    float m4 = fmaxf(fmaxf(ml[0], ml[1]), fmaxf(ml[2], ml[3]));
    float se = __expf(ml[0] - m4) + __expf(ml[1] - m4) +
               __expf(ml[2] - m4) + __expf(ml[3] - m4);
    int c = pis[32 * w + r];
    float mls = (c == 0) ? ml[0] : (c == 1) ? ml[1] : (c == 2) ? ml[2] : ml[3];
    float amps = (lane < 32) ? (mls - m4 - __logf(se)) : 0.f;
    #pragma unroll
    for (int off = 32; off; off >>= 1) amps += __shfl_xor(amps, off);

    // phase MLP for own sample (in-wave LDS ordering; no barrier)
    const float* xst = xs + 64 * w;
    float p1 = bp1[lane];
    #pragma unroll 4
    for (int d = 0; d < 64; ++d)
      p1 = fmaf(xst[d], wp1[d * 64 + lane], p1);
    p1 = fmaxf(p1, 0.f);
    phb[64 * w + lane] = p1;
    float p2 = bp2[lane];
    #pragma unroll 4
    for (int d = 0; d < 64; ++d)
      p2 = fmaf(phb[64 * w + d], wp2[d * 64 + lane], p2);
    p2 = fmaxf(p2, 0.f);
    float p3 = p2 * wp3[lane];
    #pragma unroll
    for (int off = 32; off; off >>= 1) p3 += __shfl_xor(p3, off);
    float ph = p3 + bp3[0];

    if (lane == 0 && (w == 0 || valid1)) {
      int S = 2 * s2 + w;
      float amp = expf(0.5f * amps);
      if (out_pairs) {
        out[2 * S]     = amp * cosf(ph);
        out[2 * S + 1] = amp * sinf(ph);
      } else {
        // harness flattened complex64 via astype(float32): real part only
        out[S] = amp * cosf(ph);
      }
    }
  }
}

extern "C" void kernel_launch(void* const* d_in, const int* in_sizes, int n_in,
                              void* d_out, int out_size, void* d_ws, size_t ws_size,
                              hipStream_t stream) {
  (void)n_in; (void)d_ws; (void)ws_size;
  const int B = in_sizes[0] / 64;
  const int out_pairs = (out_size >= 2 * B) ? 1 : 0;
  const int grid = (B + 1) / 2;
  dwf_kernel<<<grid, 256, 0, stream>>>(
      (const float*)d_in[0],  (const float*)d_in[1],  (const float*)d_in[2],
      (const float*)d_in[3],  (const float*)d_in[4],  (const float*)d_in[5],
      (const float*)d_in[6],  (const float*)d_in[7],  (const float*)d_in[8],
      (const float*)d_in[9],  (const float*)d_in[10], (const float*)d_in[11],
      (const float*)d_in[12], (const float*)d_in[13], (const float*)d_in[14],
      (const float*)d_in[15], (const float*)d_in[16], (const float*)d_in[17],
      (const float*)d_in[18], (const float*)d_in[19], (const float*)d_in[20],
      (const float*)d_in[21], (const float*)d_in[22], (const float*)d_in[23],
      (const float*)d_in[24], (float*)d_out, out_pairs, B);
}